// Round 9
// baseline (478.737 us; speedup 1.0000x reference)
//
#include <hip/hip_runtime.h>
#include <hip/hip_fp16.h>

#define BATCH 16
#define NROW 1024
#define MCOL 1024
#define DFEAT 128

// DP blocking: one wave per batch, 16 rows/thread, 8 cols/phase
#define R_DP 16
#define C_DP 8
#define NCH (MCOL / C_DP)   // 128 chunks along j
#define NPH (NCH + 63)      // 191 phases

#define L2E 1.4426950408889634f
#define LN2 0.6931471805599453f

typedef __attribute__((ext_vector_type(8))) short short8;
typedef __attribute__((ext_vector_type(4))) float f32x4;

__device__ inline unsigned short f2bf(float f) {  // RNE f32 -> bf16 bits
  unsigned u = __float_as_uint(f);
  return (unsigned short)((u + 0x7fff + ((u >> 16) & 1)) >> 16);
}

// ---------------------------------------------------------------------------
// Kernel 1: normalize rows and emit bf16 copies. One wave per row.
// ---------------------------------------------------------------------------
__global__ __launch_bounds__(256) void norm_kernel(
    const float* __restrict__ x, const float* __restrict__ y,
    unsigned short* __restrict__ xnb, unsigned short* __restrict__ ynb) {
  int row = blockIdx.x * 4 + (threadIdx.x >> 6);
  int lane = threadIdx.x & 63;
  const float* src;
  unsigned short* dst;
  if (row < BATCH * NROW) {
    src = x + (size_t)row * DFEAT;
    dst = xnb + (size_t)row * DFEAT;
  } else {
    int r2 = row - BATCH * NROW;
    src = y + (size_t)r2 * DFEAT;
    dst = ynb + (size_t)r2 * DFEAT;
  }
  float2 v = *(const float2*)(src + lane * 2);
  float s = v.x * v.x + v.y * v.y;
  #pragma unroll
  for (int o = 32; o > 0; o >>= 1) s += __shfl_xor(s, o, 64);
  float inv = 1.0f / (sqrtf(s) + 1e-8f);
  unsigned short b0 = f2bf(v.x * inv), b1 = f2bf(v.y * inv);
  *(unsigned*)(dst + lane * 2) = (unsigned)b0 | ((unsigned)b1 << 16);
}

// ---------------------------------------------------------------------------
// Kernel 2: MFMA distance GEMM, 128x128 tile/block, 4 waves (2x2 of 64x64),
// bf16 16x16x32 MFMA; epilogue stores exp(-(1-dot)) as fp16 row-major.
// LDS XOR-swizzle (byte ^= (row&7)<<4) kills the 16-way LDA bank conflict.
// ---------------------------------------------------------------------------
__global__ __launch_bounds__(256) void dist_kernel(
    const unsigned short* __restrict__ xnb, const unsigned short* __restrict__ ynb,
    __half* __restrict__ Dexp) {
  __shared__ __align__(16) unsigned char xsb[128 * 256];
  __shared__ __align__(16) unsigned char ysb[128 * 256];

  int b = blockIdx.z, ti0 = blockIdx.y, tj0 = blockIdx.x;
  int I0 = ti0 * 128, J0 = tj0 * 128;
  int tid = threadIdx.x;

  const uint4* xsrc = (const uint4*)(xnb + (size_t)(b * NROW + I0) * DFEAT);
  const uint4* ysrc = (const uint4*)(ynb + (size_t)(b * MCOL + J0) * DFEAT);
  #pragma unroll
  for (int it = 0; it < 8; ++it) {
    int idx = tid + it * 256;           // 0..2047: row = idx>>4, 16B col = idx&15
    int row = idx >> 4, cb = (idx & 15) * 16;
    int swz = row * 256 + (cb ^ ((row & 7) << 4));
    *(uint4*)&xsb[swz] = xsrc[idx];
    *(uint4*)&ysb[swz] = ysrc[idx];
  }
  __syncthreads();

  int wid = tid >> 6, lane = tid & 63;
  int wi = wid >> 1, wj = wid & 1;      // 64x64 quadrant
  int lr = lane & 15, lk = lane >> 4;   // frag row = lr, k-group = lk

  f32x4 acc[4][4] = {};
  #pragma unroll
  for (int ks = 0; ks < 4; ++ks) {
    int cb = ks * 64 + lk * 16;
    short8 af[4], bf[4];
    #pragma unroll
    for (int ti = 0; ti < 4; ++ti) {
      int row = wi * 64 + ti * 16 + lr;
      af[ti] = *(short8*)&xsb[row * 256 + (cb ^ ((row & 7) << 4))];
    }
    #pragma unroll
    for (int tj = 0; tj < 4; ++tj) {
      int row = wj * 64 + tj * 16 + lr;
      bf[tj] = *(short8*)&ysb[row * 256 + (cb ^ ((row & 7) << 4))];
    }
    #pragma unroll
    for (int ti = 0; ti < 4; ++ti)
      #pragma unroll
      for (int tj = 0; tj < 4; ++tj)
        acc[ti][tj] = __builtin_amdgcn_mfma_f32_16x16x32_bf16(
            af[ti], bf[tj], acc[ti][tj], 0, 0, 0);
  }

  // epilogue: C/D layout col=lane&15, row=(lane>>4)*4+v
  #pragma unroll
  for (int ti = 0; ti < 4; ++ti) {
    #pragma unroll
    for (int tj = 0; tj < 4; ++tj) {
      int gi = I0 + wi * 64 + ti * 16 + lk * 4;
      int gj = J0 + wj * 64 + tj * 16 + lr;
      #pragma unroll
      for (int v = 0; v < 4; ++v) {
        float d = 1.0f - acc[ti][tj][v];
        Dexp[((size_t)b * NROW + gi + v) * MCOL + gj] = __float2half(exp2f(-d * L2E));
      }
    }
  }
}

// ---------------------------------------------------------------------------
// Kernel 3: wave-autonomous exp-domain soft-DTW DP, LDS-staged.
// One 64-lane wave (= one block/CU) per batch: thread t owns rows
// 16t..16t+15; phase p handles chunk c = p - t (8 cols). Handoff via
// shfl_up — no barriers (single wave). Staging: global_load_lds into a
// double-buffered LDS tile (registers NEVER hold staged data — r7/r8
// showed the allocator won't keep a 16xuint4 prefetch window in VGPRs),
// counted s_waitcnt vmcnt(16) so the 16 just-issued prefetches stay in
// flight. Math identical to the r5-verified recurrence (E = exp(O - R);
// renorm E *= 2^-ex  =>  O -= ex*ln2).
// ---------------------------------------------------------------------------
typedef unsigned int u32;
__device__ inline void gload16(const void* g, void* l) {
  __builtin_amdgcn_global_load_lds(
      (const __attribute__((address_space(1))) u32*)g,
      (__attribute__((address_space(3))) u32*)l, 16, 0, 0);
}

__device__ inline void unpack8(uint4 v, float* e) {
  const __half2* h = reinterpret_cast<const __half2*>(&v);
  #pragma unroll
  for (int q = 0; q < 4; ++q) {
    float2 f = __half22float2(h[q]);
    e[2 * q] = f.x;
    e[2 * q + 1] = f.y;
  }
}

__global__ __launch_bounds__(64, 1) void dtw_kernel(
    const __half* __restrict__ Dexp, float* __restrict__ out) {
  int b = blockIdx.x;
  int t = threadIdx.x;                  // 0..63, thread-in-batch

  __shared__ __align__(16) uint4 buf[2][R_DP][64];   // 32 KB double buffer

  const __half* Db = Dexp + ((size_t)b * NROW + (size_t)t * R_DP) * MCOL;

  float carry[R_DP];
  #pragma unroll
  for (int r = 0; r < R_DP; ++r) carry[r] = 0.0f;
  float B[C_DP + 1] = {};
  float O = 0.0f;

  // prologue: stage phase-0 chunk (c = -t clamps to 0) into buf[0]
  #pragma unroll
  for (int r = 0; r < R_DP; ++r)
    gload16(Db + (size_t)r * MCOL, &buf[0][r][0]);

  for (int p = 0; p < NPH; ++p) {
    int c = p - t;
    int par = p & 1;

    // prefetch phase p+1's chunk into the other buffer (clamped address)
    int cn = (c + 1) < 0 ? 0 : ((c + 1) >= NCH ? NCH - 1 : (c + 1));
    const __half* gsrc = Db + cn * C_DP;
    #pragma unroll
    for (int r = 0; r < R_DP; ++r)
      gload16(gsrc + (size_t)r * MCOL, &buf[par ^ 1][r][0]);

    // wait for THIS phase's data (issued last phase); 16 newest stay in flight
    asm volatile("s_waitcnt vmcnt(16)" ::: "memory");

    float U[C_DP + 1];
    #pragma unroll
    for (int k = 0; k <= C_DP; ++k) U[k] = __shfl_up(B[k], 1, 64);
    float Oin = __shfl_up(O, 1, 64);
    if (t == 0) {
      #pragma unroll
      for (int k = 0; k <= C_DP; ++k) U[k] = 0.0f;
      U[0] = (c == 0) ? 1.0f : 0.0f;    // E[0][0] = exp(-0)
      Oin = O;
    }

    if (c >= 0 && c < NCH) {
      if (c == 0) O = Oin;              // adopt neighbor's frame at activation
      float sc = exp2f((O - Oin) * L2E);
      #pragma unroll
      for (int k = 0; k <= C_DP; ++k) U[k] *= sc;

      const uint4* bp = &buf[par][0][0] + t;   // row stride = 64 uint4

      #pragma unroll
      for (int r = 0; r < R_DP; ++r) {
        float e[C_DP];
        unpack8(bp[r * 64], e);
        float A[C_DP];
        #pragma unroll
        for (int k = 0; k < C_DP; ++k) A[k] = e[k] * (U[k] + U[k + 1]);
        float oldc = carry[r];
        float left = oldc;
        float V[C_DP];
        #pragma unroll
        for (int k = 0; k < C_DP; ++k) {
          left = fmaf(e[k], left, A[k]);  // E = expd*(Eup+Eupleft+Eleft)
          V[k] = left;
        }
        U[0] = oldc;
        #pragma unroll
        for (int k = 1; k <= C_DP; ++k) U[k] = V[k - 1];
        carry[r] = V[C_DP - 1];
      }

      // renormalize via exponent bits (E *= 2^-ex  =>  O -= ex*ln2)
      float rep = carry[R_DP - 1];
      if (rep > 0.0f) {
        int ex = (int)((__float_as_uint(rep) >> 23) & 0xFF) - 127;
        if ((ex < -8 || ex > 8) && ex < 128) {
          float s = __uint_as_float((unsigned)(127 - ex) << 23);  // 2^-ex
          #pragma unroll
          for (int r = 0; r < R_DP; ++r) carry[r] *= s;
          #pragma unroll
          for (int k = 0; k <= C_DP; ++k) U[k] *= s;
          O -= (float)ex * LN2;
        }
      }
      #pragma unroll
      for (int k = 0; k <= C_DP; ++k) B[k] = U[k];
    }
  }

  // don't end the wave with an in-flight LDS DMA
  asm volatile("s_waitcnt vmcnt(0)" ::: "memory");

  if (t == 63) out[b] = O - logf(carry[R_DP - 1]);  // R[N][M]
}

// ---------------------------------------------------------------------------
extern "C" void kernel_launch(void* const* d_in, const int* in_sizes, int n_in,
                              void* d_out, int out_size, void* d_ws, size_t ws_size,
                              hipStream_t stream) {
  const float* x = (const float*)d_in[0];
  const float* y = (const float*)d_in[1];
  float* out = (float*)d_out;

  char* ws = (char*)d_ws;
  __half* Dexp = (__half*)ws;
  size_t dd_bytes = (size_t)BATCH * NROW * MCOL * sizeof(__half);  // 33.5 MB
  unsigned short* xnb = (unsigned short*)(ws + dd_bytes);          // 4 MB
  unsigned short* ynb = xnb + (size_t)BATCH * NROW * DFEAT;        // 4 MB

  norm_kernel<<<(2 * BATCH * NROW) / 4, 256, 0, stream>>>(x, y, xnb, ynb);
  dist_kernel<<<dim3(MCOL / 128, NROW / 128, BATCH), 256, 0, stream>>>(
      xnb, ynb, Dexp);
  dtw_kernel<<<BATCH, 64, 0, stream>>>(Dexp, out);
}

// Round 10
// 340.362 us; speedup vs baseline: 1.4066x; 1.4066x over previous
//
#include <hip/hip_runtime.h>
#include <hip/hip_fp16.h>

#define BATCH 16
#define NROW 1024
#define MCOL 1024
#define DFEAT 128

// DP blocking: one wave per batch, 16 rows/thread, 8 cols/phase
#define R_DP 16
#define C_DP 8
#define NCH (MCOL / C_DP)   // 128 chunks along j
#define NPH (NCH + 63)      // 191 phases

#define L2E 1.4426950408889634f
#define LN2 0.6931471805599453f

typedef __attribute__((ext_vector_type(8))) short short8;
typedef __attribute__((ext_vector_type(4))) float f32x4;

__device__ inline unsigned short f2bf(float f) {  // RNE f32 -> bf16 bits
  unsigned u = __float_as_uint(f);
  return (unsigned short)((u + 0x7fff + ((u >> 16) & 1)) >> 16);
}

// ---------------------------------------------------------------------------
// Kernel 1: normalize rows and emit bf16 copies. One wave per row.
// ---------------------------------------------------------------------------
__global__ __launch_bounds__(256) void norm_kernel(
    const float* __restrict__ x, const float* __restrict__ y,
    unsigned short* __restrict__ xnb, unsigned short* __restrict__ ynb) {
  int row = blockIdx.x * 4 + (threadIdx.x >> 6);
  int lane = threadIdx.x & 63;
  const float* src;
  unsigned short* dst;
  if (row < BATCH * NROW) {
    src = x + (size_t)row * DFEAT;
    dst = xnb + (size_t)row * DFEAT;
  } else {
    int r2 = row - BATCH * NROW;
    src = y + (size_t)r2 * DFEAT;
    dst = ynb + (size_t)r2 * DFEAT;
  }
  float2 v = *(const float2*)(src + lane * 2);
  float s = v.x * v.x + v.y * v.y;
  #pragma unroll
  for (int o = 32; o > 0; o >>= 1) s += __shfl_xor(s, o, 64);
  float inv = 1.0f / (sqrtf(s) + 1e-8f);
  unsigned short b0 = f2bf(v.x * inv), b1 = f2bf(v.y * inv);
  *(unsigned*)(dst + lane * 2) = (unsigned)b0 | ((unsigned)b1 << 16);
}

// ---------------------------------------------------------------------------
// Kernel 2: MFMA distance GEMM, 128x128 tile/block, 4 waves (2x2 of 64x64),
// bf16 16x16x32 MFMA. Epilogue stores exp(-(1-dot)) as fp16 in PHASE-MAJOR
// layout: Dphase[b][p][r][lane][k] with lane=i>>4, r=i&15, c=j>>3, k=j&7,
// p=c+lane — so the 16 KB a DP wave consumes at phase p is contiguous.
// ---------------------------------------------------------------------------
__global__ __launch_bounds__(256) void dist_kernel(
    const unsigned short* __restrict__ xnb, const unsigned short* __restrict__ ynb,
    __half* __restrict__ Dphase) {
  __shared__ __align__(16) unsigned char xsb[128 * 256];
  __shared__ __align__(16) unsigned char ysb[128 * 256];

  int b = blockIdx.z, ti0 = blockIdx.y, tj0 = blockIdx.x;
  int I0 = ti0 * 128, J0 = tj0 * 128;
  int tid = threadIdx.x;

  const uint4* xsrc = (const uint4*)(xnb + (size_t)(b * NROW + I0) * DFEAT);
  const uint4* ysrc = (const uint4*)(ynb + (size_t)(b * MCOL + J0) * DFEAT);
  #pragma unroll
  for (int it = 0; it < 8; ++it) {
    int idx = tid + it * 256;           // 0..2047: row = idx>>4, 16B col = idx&15
    int row = idx >> 4, cb = (idx & 15) * 16;
    int swz = row * 256 + (cb ^ ((row & 7) << 4));
    *(uint4*)&xsb[swz] = xsrc[idx];
    *(uint4*)&ysb[swz] = ysrc[idx];
  }
  __syncthreads();

  int wid = tid >> 6, lane = tid & 63;
  int wi = wid >> 1, wj = wid & 1;      // 64x64 quadrant
  int lr = lane & 15, lk = lane >> 4;   // frag row = lr, k-group = lk

  f32x4 acc[4][4] = {};
  #pragma unroll
  for (int ks = 0; ks < 4; ++ks) {
    int cb = ks * 64 + lk * 16;
    short8 af[4], bf[4];
    #pragma unroll
    for (int ti = 0; ti < 4; ++ti) {
      int row = wi * 64 + ti * 16 + lr;
      af[ti] = *(short8*)&xsb[row * 256 + (cb ^ ((row & 7) << 4))];
    }
    #pragma unroll
    for (int tj = 0; tj < 4; ++tj) {
      int row = wj * 64 + tj * 16 + lr;
      bf[tj] = *(short8*)&ysb[row * 256 + (cb ^ ((row & 7) << 4))];
    }
    #pragma unroll
    for (int ti = 0; ti < 4; ++ti)
      #pragma unroll
      for (int tj = 0; tj < 4; ++tj)
        acc[ti][tj] = __builtin_amdgcn_mfma_f32_16x16x32_bf16(
            af[ti], bf[tj], acc[ti][tj], 0, 0, 0);
  }

  // epilogue: C/D layout col=lane&15, row=(lane>>4)*4+v; phase-major store
  #pragma unroll
  for (int ti = 0; ti < 4; ++ti) {
    int gi0 = I0 + wi * 64 + ti * 16;   // 16-aligned
    int l = gi0 >> 4;                   // DP lane owning these rows
    #pragma unroll
    for (int tj = 0; tj < 4; ++tj) {
      int gj = J0 + wj * 64 + tj * 16 + lr;
      int c = gj >> 3, k = gj & 7;
      int p = c + l;
      #pragma unroll
      for (int v = 0; v < 4; ++v) {
        int r = lk * 4 + v;
        float d = 1.0f - acc[ti][tj][v];
        size_t off = ((((size_t)b * NPH + p) * R_DP + r) * 64 + l) * C_DP + k;
        Dphase[off] = __float2half(exp2f(-d * L2E));
      }
    }
  }
}

// ---------------------------------------------------------------------------
// Kernel 3: wave-autonomous exp-domain soft-DTW DP, phase-major staged.
// One 64-lane wave (= one block/CU) per batch: lane t owns rows 16t..16t+15;
// phase p handles chunk c = p - t (8 cols). Handoff via shfl_up — no
// barriers. Staging: per phase, 16 fully-COALESCED global_load_lds (wave-
// uniform base + lane*16B — the phase-major layout kills the 64-way address
// scatter that stalled r8/r9), double-buffered, counted vmcnt(16). Consume
// via a manual 3-deep ds_read window (12 VGPRs) so ds latency hides under
// row compute. Math identical to the r5-verified recurrence (E = exp(O-R);
// renorm E *= 2^-ex  =>  O -= ex*ln2).
// ---------------------------------------------------------------------------
typedef unsigned int u32;
__device__ inline void gload16(const void* g, void* l) {
  __builtin_amdgcn_global_load_lds(
      (const __attribute__((address_space(1))) u32*)g,
      (__attribute__((address_space(3))) u32*)l, 16, 0, 0);
}

__device__ inline void unpack8(uint4 v, float* e) {
  const __half2* h = reinterpret_cast<const __half2*>(&v);
  #pragma unroll
  for (int q = 0; q < 4; ++q) {
    float2 f = __half22float2(h[q]);
    e[2 * q] = f.x;
    e[2 * q + 1] = f.y;
  }
}

__global__ __launch_bounds__(64, 1) void dtw_kernel(
    const __half* __restrict__ Dphase, float* __restrict__ out) {
  int b = blockIdx.x;
  int t = threadIdx.x;                  // 0..63, lane = DP row-block owner

  __shared__ __align__(16) uint4 buf[2][R_DP][64];   // 32 KB double buffer

  // per-lane source: slot (b, q, r, t); row stride 512 halfs, phase stride 16*512
  const __half* Pb = Dphase + (size_t)b * NPH * R_DP * 512 + (size_t)t * C_DP;

  float carry[R_DP];
  #pragma unroll
  for (int r = 0; r < R_DP; ++r) carry[r] = 0.0f;
  float B[C_DP + 1] = {};
  float O = 0.0f;

  // prologue: stage phase 0 into buf[0]
  #pragma unroll
  for (int r = 0; r < R_DP; ++r)
    gload16(Pb + (size_t)r * 512, &buf[0][r][0]);

  for (int p = 0; p < NPH; ++p) {
    int par = p & 1;
    int c = p - t;

    // prefetch phase p+1 (wave-uniform base; clamp only the phase index)
    int q = (p + 1 < NPH) ? p + 1 : NPH - 1;
    const __half* gsrc = Pb + (size_t)q * (R_DP * 512);
    #pragma unroll
    for (int r = 0; r < R_DP; ++r)
      gload16(gsrc + (size_t)r * 512, &buf[par ^ 1][r][0]);

    // wait for THIS phase's 16 (issued last iter); the 16 newest stay in flight
    asm volatile("s_waitcnt vmcnt(16)" ::: "memory");

    float U[C_DP + 1];
    #pragma unroll
    for (int k = 0; k <= C_DP; ++k) U[k] = __shfl_up(B[k], 1, 64);
    float Oin = __shfl_up(O, 1, 64);
    if (t == 0) {
      #pragma unroll
      for (int k = 0; k <= C_DP; ++k) U[k] = 0.0f;
      U[0] = (c == 0) ? 1.0f : 0.0f;    // E[0][0] = exp(-0)
      Oin = O;
    }

    if (c >= 0 && c < NCH) {
      if (c == 0) O = Oin;              // adopt neighbor's frame at activation
      float sc = exp2f((O - Oin) * L2E);
      #pragma unroll
      for (int k = 0; k <= C_DP; ++k) U[k] *= sc;

      const uint4* bp = &buf[par][0][0] + t;   // row stride = 64 uint4

      // 3-deep ds_read window: load r+2 while computing r
      uint4 w0 = bp[0];
      uint4 w1 = bp[64];
      #pragma unroll
      for (int r = 0; r < R_DP; ++r) {
        uint4 wn = (r + 2 < R_DP) ? bp[(r + 2) * 64] : w0;
        float e[C_DP];
        unpack8(w0, e);
        w0 = w1;
        w1 = wn;
        float A[C_DP];
        #pragma unroll
        for (int k = 0; k < C_DP; ++k) A[k] = e[k] * (U[k] + U[k + 1]);
        float oldc = carry[r];
        float left = oldc;
        float V[C_DP];
        #pragma unroll
        for (int k = 0; k < C_DP; ++k) {
          left = fmaf(e[k], left, A[k]);  // E = expd*(Eup+Eupleft+Eleft)
          V[k] = left;
        }
        U[0] = oldc;
        #pragma unroll
        for (int k = 1; k <= C_DP; ++k) U[k] = V[k - 1];
        carry[r] = V[C_DP - 1];
      }

      // renormalize via exponent bits (E *= 2^-ex  =>  O -= ex*ln2)
      float rep = carry[R_DP - 1];
      if (rep > 0.0f) {
        int ex = (int)((__float_as_uint(rep) >> 23) & 0xFF) - 127;
        if ((ex < -8 || ex > 8) && ex < 128) {
          float s = __uint_as_float((unsigned)(127 - ex) << 23);  // 2^-ex
          #pragma unroll
          for (int r = 0; r < R_DP; ++r) carry[r] *= s;
          #pragma unroll
          for (int k = 0; k <= C_DP; ++k) U[k] *= s;
          O -= (float)ex * LN2;
        }
      }
      #pragma unroll
      for (int k = 0; k <= C_DP; ++k) B[k] = U[k];
    }
  }

  // don't end the wave with an in-flight LDS DMA
  asm volatile("s_waitcnt vmcnt(0)" ::: "memory");

  if (t == 63) out[b] = O - logf(carry[R_DP - 1]);  // R[N][M]
}

// ---------------------------------------------------------------------------
extern "C" void kernel_launch(void* const* d_in, const int* in_sizes, int n_in,
                              void* d_out, int out_size, void* d_ws, size_t ws_size,
                              hipStream_t stream) {
  const float* x = (const float*)d_in[0];
  const float* y = (const float*)d_in[1];
  float* out = (float*)d_out;

  char* ws = (char*)d_ws;
  __half* Dphase = (__half*)ws;
  size_t dp_bytes = (size_t)BATCH * NPH * R_DP * 512 * sizeof(__half); // ~50 MB
  unsigned short* xnb = (unsigned short*)(ws + dp_bytes);              // 4 MB
  unsigned short* ynb = xnb + (size_t)BATCH * NROW * DFEAT;            // 4 MB

  norm_kernel<<<(2 * BATCH * NROW) / 4, 256, 0, stream>>>(x, y, xnb, ynb);
  dist_kernel<<<dim3(MCOL / 128, NROW / 128, BATCH), 256, 0, stream>>>(
      xnb, ynb, Dphase);
  dtw_kernel<<<BATCH, 64, 0, stream>>>(Dphase, out);
}

// Round 11
// 270.532 us; speedup vs baseline: 1.7696x; 1.2581x over previous
//
#include <hip/hip_runtime.h>
#include <hip/hip_fp16.h>

#define BATCH 16
#define NROW 1024
#define MCOL 1024
#define DFEAT 128

// DP blocking: one wave per batch, 16 rows/thread, 8 cols/phase
#define R_DP 16
#define C_DP 8
#define NCH (MCOL / C_DP)   // 128 chunks along j
#define NPH (NCH + 63)      // 191 phases (192 executed, +pad)
#define PSTRIDE (NPH + 2)   // phase slots allocated per batch (2 pad phases)

#define L2E 1.4426950408889634f
#define LN2 0.6931471805599453f

typedef __attribute__((ext_vector_type(8))) short short8;
typedef __attribute__((ext_vector_type(4))) float f32x4;

__device__ inline unsigned short f2bf(float f) {  // RNE f32 -> bf16 bits
  unsigned u = __float_as_uint(f);
  return (unsigned short)((u + 0x7fff + ((u >> 16) & 1)) >> 16);
}

// ---------------------------------------------------------------------------
// Kernel 1: normalize rows and emit bf16 copies. One wave per row.
// ---------------------------------------------------------------------------
__global__ __launch_bounds__(256) void norm_kernel(
    const float* __restrict__ x, const float* __restrict__ y,
    unsigned short* __restrict__ xnb, unsigned short* __restrict__ ynb) {
  int row = blockIdx.x * 4 + (threadIdx.x >> 6);
  int lane = threadIdx.x & 63;
  const float* src;
  unsigned short* dst;
  if (row < BATCH * NROW) {
    src = x + (size_t)row * DFEAT;
    dst = xnb + (size_t)row * DFEAT;
  } else {
    int r2 = row - BATCH * NROW;
    src = y + (size_t)r2 * DFEAT;
    dst = ynb + (size_t)r2 * DFEAT;
  }
  float2 v = *(const float2*)(src + lane * 2);
  float s = v.x * v.x + v.y * v.y;
  #pragma unroll
  for (int o = 32; o > 0; o >>= 1) s += __shfl_xor(s, o, 64);
  float inv = 1.0f / (sqrtf(s) + 1e-8f);
  unsigned short b0 = f2bf(v.x * inv), b1 = f2bf(v.y * inv);
  *(unsigned*)(dst + lane * 2) = (unsigned)b0 | ((unsigned)b1 << 16);
}

// ---------------------------------------------------------------------------
// Kernel 2: MFMA distance GEMM, 128x128 tile/block, 4 waves (2x2 of 64x64),
// bf16 16x16x32 MFMA. Epilogue stores exp(-(1-dot)) as fp16 in PHASE-MAJOR
// layout: Dphase[b][p][r][lane][k], p = (j>>3) + (i>>4), r = i&15, k = j&7 —
// the 16 KB a DP wave consumes at phase p is contiguous, and lane l's slot
// sits at lane-offset l (so a coalesced dwordx4 read IS the distribution).
// ---------------------------------------------------------------------------
__global__ __launch_bounds__(256) void dist_kernel(
    const unsigned short* __restrict__ xnb, const unsigned short* __restrict__ ynb,
    __half* __restrict__ Dphase) {
  __shared__ __align__(16) unsigned char xsb[128 * 256];
  __shared__ __align__(16) unsigned char ysb[128 * 256];

  int b = blockIdx.z, ti0 = blockIdx.y, tj0 = blockIdx.x;
  int I0 = ti0 * 128, J0 = tj0 * 128;
  int tid = threadIdx.x;

  const uint4* xsrc = (const uint4*)(xnb + (size_t)(b * NROW + I0) * DFEAT);
  const uint4* ysrc = (const uint4*)(ynb + (size_t)(b * MCOL + J0) * DFEAT);
  #pragma unroll
  for (int it = 0; it < 8; ++it) {
    int idx = tid + it * 256;           // 0..2047: row = idx>>4, 16B col = idx&15
    int row = idx >> 4, cb = (idx & 15) * 16;
    int swz = row * 256 + (cb ^ ((row & 7) << 4));
    *(uint4*)&xsb[swz] = xsrc[idx];
    *(uint4*)&ysb[swz] = ysrc[idx];
  }
  __syncthreads();

  int wid = tid >> 6, lane = tid & 63;
  int wi = wid >> 1, wj = wid & 1;      // 64x64 quadrant
  int lr = lane & 15, lk = lane >> 4;   // frag row = lr, k-group = lk

  f32x4 acc[4][4] = {};
  #pragma unroll
  for (int ks = 0; ks < 4; ++ks) {
    int cb = ks * 64 + lk * 16;
    short8 af[4], bf[4];
    #pragma unroll
    for (int ti = 0; ti < 4; ++ti) {
      int row = wi * 64 + ti * 16 + lr;
      af[ti] = *(short8*)&xsb[row * 256 + (cb ^ ((row & 7) << 4))];
    }
    #pragma unroll
    for (int tj = 0; tj < 4; ++tj) {
      int row = wj * 64 + tj * 16 + lr;
      bf[tj] = *(short8*)&ysb[row * 256 + (cb ^ ((row & 7) << 4))];
    }
    #pragma unroll
    for (int ti = 0; ti < 4; ++ti)
      #pragma unroll
      for (int tj = 0; tj < 4; ++tj)
        acc[ti][tj] = __builtin_amdgcn_mfma_f32_16x16x32_bf16(
            af[ti], bf[tj], acc[ti][tj], 0, 0, 0);
  }

  // epilogue: C/D layout col=lane&15, row=(lane>>4)*4+v; phase-major store
  #pragma unroll
  for (int ti = 0; ti < 4; ++ti) {
    int gi0 = I0 + wi * 64 + ti * 16;   // 16-aligned
    int l = gi0 >> 4;                   // DP lane owning these rows
    #pragma unroll
    for (int tj = 0; tj < 4; ++tj) {
      int gj = J0 + wj * 64 + tj * 16 + lr;
      int c = gj >> 3, k = gj & 7;
      int p = c + l;
      #pragma unroll
      for (int v = 0; v < 4; ++v) {
        int r = lk * 4 + v;
        float d = 1.0f - acc[ti][tj][v];
        size_t off = ((((size_t)b * PSTRIDE + p) * R_DP + r) * 64 + l) * C_DP + k;
        Dphase[off] = __float2half(exp2f(-d * L2E));
      }
    }
  }
}

// ---------------------------------------------------------------------------
// Kernel 3: wave-autonomous exp-domain soft-DTW DP, ZERO LDS.
// One 64-lane wave (= one block/CU) per batch: lane t owns rows 16t..16t+15;
// phase p handles chunk c = p - t (8 cols). Handoff via shfl_up only.
// Phase-major layout => lane t's row-r data = coalesced dwordx4 at
// base + r*1024 + t*16, read DIRECTLY into registers. The 16-load prefetch
// window is pinned in VGPRs with inline-asm volatile loads (r7/r8: plain
// loads get sunk by regalloc; r9/r10: LDS-DMA retires ~1 fill/250cyc —
// throughput-bound). Counted vmcnt(16) + sched_barrier(0) (rule #18).
// Math identical to the r5-verified recurrence (E = exp(O-R); renorm
// E *= 2^-ex  =>  O -= ex*ln2).
// ---------------------------------------------------------------------------
__device__ inline void unpack8(uint4 v, float* e) {
  const __half2* h = reinterpret_cast<const __half2*>(&v);
  #pragma unroll
  for (int q = 0; q < 4; ++q) {
    float2 f = __half22float2(h[q]);
    e[2 * q] = f.x;
    e[2 * q + 1] = f.y;
  }
}

// issue 16 coalesced dwordx4 loads for one phase into register set L
#define ISSUE16(L, B0, B1, B2, B3)                                           \
  asm volatile("global_load_dwordx4 %0, %1, off"             : "=v"(L[0])  : "v"(B0)); \
  asm volatile("global_load_dwordx4 %0, %1, off offset:1024" : "=v"(L[1])  : "v"(B0)); \
  asm volatile("global_load_dwordx4 %0, %1, off offset:2048" : "=v"(L[2])  : "v"(B0)); \
  asm volatile("global_load_dwordx4 %0, %1, off offset:3072" : "=v"(L[3])  : "v"(B0)); \
  asm volatile("global_load_dwordx4 %0, %1, off"             : "=v"(L[4])  : "v"(B1)); \
  asm volatile("global_load_dwordx4 %0, %1, off offset:1024" : "=v"(L[5])  : "v"(B1)); \
  asm volatile("global_load_dwordx4 %0, %1, off offset:2048" : "=v"(L[6])  : "v"(B1)); \
  asm volatile("global_load_dwordx4 %0, %1, off offset:3072" : "=v"(L[7])  : "v"(B1)); \
  asm volatile("global_load_dwordx4 %0, %1, off"             : "=v"(L[8])  : "v"(B2)); \
  asm volatile("global_load_dwordx4 %0, %1, off offset:1024" : "=v"(L[9])  : "v"(B2)); \
  asm volatile("global_load_dwordx4 %0, %1, off offset:2048" : "=v"(L[10]) : "v"(B2)); \
  asm volatile("global_load_dwordx4 %0, %1, off offset:3072" : "=v"(L[11]) : "v"(B2)); \
  asm volatile("global_load_dwordx4 %0, %1, off"             : "=v"(L[12]) : "v"(B3)); \
  asm volatile("global_load_dwordx4 %0, %1, off offset:1024" : "=v"(L[13]) : "v"(B3)); \
  asm volatile("global_load_dwordx4 %0, %1, off offset:2048" : "=v"(L[14]) : "v"(B3)); \
  asm volatile("global_load_dwordx4 %0, %1, off offset:3072" : "=v"(L[15]) : "v"(B3));

#define COMPUTE(P, L)                                                        \
  {                                                                          \
    int c = (P) - t;                                                         \
    float U[C_DP + 1];                                                       \
    _Pragma("unroll")                                                        \
    for (int k = 0; k <= C_DP; ++k) U[k] = __shfl_up(B[k], 1, 64);           \
    float Oin = __shfl_up(O, 1, 64);                                         \
    if (t == 0) {                                                            \
      _Pragma("unroll")                                                      \
      for (int k = 0; k <= C_DP; ++k) U[k] = 0.0f;                           \
      U[0] = (c == 0) ? 1.0f : 0.0f;                                         \
      Oin = O;                                                               \
    }                                                                        \
    if (c >= 0 && c < NCH) {                                                 \
      if (c == 0) O = Oin;                                                   \
      float sc = exp2f((O - Oin) * L2E);                                     \
      _Pragma("unroll")                                                      \
      for (int k = 0; k <= C_DP; ++k) U[k] *= sc;                            \
      _Pragma("unroll")                                                      \
      for (int r = 0; r < R_DP; ++r) {                                       \
        float e[C_DP];                                                       \
        unpack8(L[r], e);                                                    \
        float A[C_DP];                                                       \
        _Pragma("unroll")                                                    \
        for (int k = 0; k < C_DP; ++k) A[k] = e[k] * (U[k] + U[k + 1]);      \
        float oldc = carry[r];                                               \
        float left = oldc;                                                   \
        float V[C_DP];                                                       \
        _Pragma("unroll")                                                    \
        for (int k = 0; k < C_DP; ++k) {                                     \
          left = fmaf(e[k], left, A[k]);                                     \
          V[k] = left;                                                       \
        }                                                                    \
        U[0] = oldc;                                                         \
        _Pragma("unroll")                                                    \
        for (int k = 1; k <= C_DP; ++k) U[k] = V[k - 1];                     \
        carry[r] = V[C_DP - 1];                                              \
      }                                                                      \
      float rep = carry[R_DP - 1];                                           \
      if (rep > 0.0f) {                                                      \
        int ex = (int)((__float_as_uint(rep) >> 23) & 0xFF) - 127;           \
        if ((ex < -8 || ex > 8) && ex < 128) {                               \
          float s = __uint_as_float((unsigned)(127 - ex) << 23);             \
          _Pragma("unroll")                                                  \
          for (int r = 0; r < R_DP; ++r) carry[r] *= s;                      \
          _Pragma("unroll")                                                  \
          for (int k = 0; k <= C_DP; ++k) U[k] *= s;                         \
          O -= (float)ex * LN2;                                              \
        }                                                                    \
      }                                                                      \
      _Pragma("unroll")                                                      \
      for (int k = 0; k <= C_DP; ++k) B[k] = U[k];                           \
    }                                                                        \
  }

#define WAIT16()                                      \
  asm volatile("s_waitcnt vmcnt(16)" ::: "memory");   \
  __builtin_amdgcn_sched_barrier(0);

__global__ __launch_bounds__(64, 1) void dtw_kernel(
    const __half* __restrict__ Dphase, float* __restrict__ out) {
  int b = blockIdx.x;
  int t = threadIdx.x;                  // 0..63, lane = DP row-block owner

  // per-lane base for (phase 0, row 0): byte addr + t*16
  const char* g = (const char*)Dphase + (size_t)b * PSTRIDE * 16384 + t * 16;
  const char* b0 = g;                   // rows 0-3   (offsets 0..3072)
  const char* b1 = g + 4096;            // rows 4-7
  const char* b2 = g + 8192;            // rows 8-11
  const char* b3 = g + 12288;           // rows 12-15

  float carry[R_DP];
  #pragma unroll
  for (int r = 0; r < R_DP; ++r) carry[r] = 0.0f;
  float B[C_DP + 1] = {};
  float O = 0.0f;

  uint4 LA[R_DP], LB[R_DP];

  // prologue: issue phase 0 into LA
  ISSUE16(LA, b0, b1, b2, b3);

  for (int p = 0; p < 192; p += 2) {
    // even phase: prefetch p+1 into LB, consume LA
    b0 += 16384; b1 += 16384; b2 += 16384; b3 += 16384;
    ISSUE16(LB, b0, b1, b2, b3);
    WAIT16();
    COMPUTE(p, LA);

    // odd phase: prefetch p+2 into LA, consume LB
    b0 += 16384; b1 += 16384; b2 += 16384; b3 += 16384;
    ISSUE16(LA, b0, b1, b2, b3);
    WAIT16();
    COMPUTE(p + 1, LB);
  }

  asm volatile("s_waitcnt vmcnt(0)" ::: "memory");

  if (t == 63) out[b] = O - logf(carry[R_DP - 1]);  // R[N][M]
}

// ---------------------------------------------------------------------------
extern "C" void kernel_launch(void* const* d_in, const int* in_sizes, int n_in,
                              void* d_out, int out_size, void* d_ws, size_t ws_size,
                              hipStream_t stream) {
  const float* x = (const float*)d_in[0];
  const float* y = (const float*)d_in[1];
  float* out = (float*)d_out;

  char* ws = (char*)d_ws;
  __half* Dphase = (__half*)ws;
  size_t dp_bytes = (size_t)BATCH * PSTRIDE * 16384;   // ~50.6 MB (incl. pad)
  unsigned short* xnb = (unsigned short*)(ws + dp_bytes);          // 4 MB
  unsigned short* ynb = xnb + (size_t)BATCH * NROW * DFEAT;        // 4 MB

  norm_kernel<<<(2 * BATCH * NROW) / 4, 256, 0, stream>>>(x, y, xnb, ynb);
  dist_kernel<<<dim3(MCOL / 128, NROW / 128, BATCH), 256, 0, stream>>>(
      xnb, ynb, Dphase);
  dtw_kernel<<<BATCH, 64, 0, stream>>>(Dphase, out);
}